// Round 8
// baseline (26219.681 us; speedup 1.0000x reference)
//
#include <hip/hip_runtime.h>
#include <math.h>

#define SEQ 1000
#define IND 76

__device__ __forceinline__ float sigf(float v) { return 1.0f / (1.0f + expf(-v)); }

// 512 threads, 3 barriers/step, all weights register-resident, row-ownership:
//  A t[0,200)   w0-3: pair r=t>>1 (even=Wm row r, odd=Wa row r). wreg[0..99]=mem cols,
//               [100..199]=dx cols. alpha: pE = dot(mem-part, lm|lb). gamma: late dot over
//               dxP + sigmoid + pair-shfl + liquid update (even lane owns state in LDS).
//  D t[200,250) w3: L1 neuron n=t-200, 4 masked rows wreg[0..127], b1/bt1 @[128..135].
//               beta: l1 step (j+1). gamma: s1 write to kin buffers.
//  C t[256,356) w4-5: L2 neuron q=t-256, 4 masked W2 rows wreg[0..151], b2/bt2 @[152..159].
//               alpha: d2 rows + m2/s2 in-thread (no shfl), write s2P + kin2 window.
//  R t[356,364) w5: readout partials (wd chunk in wreg[0..24]); md owners t356/357.  beta.
//  X t[364,370) w5: x prefetch, 3-4 float4 each: issue alpha, write beta.
//  B t[384,484) w6-7: dx row q=t-384. wreg[0..99]=WxS (s2 cols), [100..199]=WxL (ls cols).
//               alpha: pE = dot(WxL, ls). beta: dx = (dot(WxS,s2) + pE) + bx -> dxP.
__global__ __launch_bounds__(512) void dhsnn_fwd(
    const float* __restrict__ x,
    const float* __restrict__ W1, const float* __restrict__ b1,
    const float* __restrict__ tau_m1, const float* __restrict__ tau_n1,
    const float* __restrict__ W2, const float* __restrict__ b2,
    const float* __restrict__ tau_m2, const float* __restrict__ tau_n2,
    const float* __restrict__ Wxp, const float* __restrict__ bxp,
    const float* __restrict__ Wm, const float* __restrict__ bm,
    const float* __restrict__ Wa, const float* __restrict__ ba,
    const float* __restrict__ Wd, const float* __restrict__ bd,
    const float* __restrict__ tau_md,
    float* __restrict__ out)
{
    const int t   = (int)threadIdx.x;
    const int blk = (int)blockIdx.x;

    __shared__ __align__(16) float kin1[2][128];   // [0..75] xt, [76..125] s1, [126..127]=0
    __shared__ __align__(16) float kin2[2][4][40]; // branch windows of [s1(50); s2(100)]
    __shared__ __align__(16) float s2P[100];
    __shared__ __align__(16) float dxP[100];
    __shared__ __align__(16) float lsP[100];
    __shared__ __align__(16) float lmP[100];
    __shared__ __align__(16) float lbP[100];

    for (int i = t; i < 256; i += 512) (&kin1[0][0])[i] = 0.f;
    for (int i = t; i < 320; i += 512) (&kin2[0][0][0])[i] = 0.f;
    if (t < 100) { s2P[t]=0.f; dxP[t]=0.f; lsP[t]=0.f; lmP[t]=0.f; lbP[t]=1.6f; }

    float wreg[200];
    // role-unioned persistent scalars:
    //  A: pE(early dot), gBias(bm|ba)
    //  C: gA..gD=d2, gM=m2, gS=s2, gAl=alpha2  (b2/bt2 in wreg[152..159])
    //  D: gA..gD=d1, gM=m1, gS=s1, gAl=alpha1  (b1/bt1 in wreg[128..135])
    //  B: pE(dxE), gBias(bx)
    //  R/md: gM=mdr, gS=accr, gAl=alpha_d, gBias=bd
    float pE=0.f, gA=0.f, gB=0.f, gC=0.f, gD=0.f, gM=0.f, gS=0.f, gAl=0.f, gBias=0.f;
    float4 xq0 = make_float4(0,0,0,0), xq1 = make_float4(0,0,0,0);
    float4 xq2 = make_float4(0,0,0,0), xq3 = make_float4(0,0,0,0);

    // ---- weight init ----
    if (t < 200) {                                 // A
        const int r = t >> 1;
        const float* Wrow = ((t & 1) ? Wa : Wm) + r * 200;
        #pragma unroll
        for (int u = 0; u < 100; ++u) { wreg[u] = Wrow[100 + u]; wreg[100 + u] = Wrow[u]; }
        gBias = (t & 1) ? ba[r] : bm[r];
    } else if (t < 250) {                          // D
        const int n = t - 200;
        #pragma unroll
        for (int k = 0; k < 4; ++k) {
            #pragma unroll
            for (int u = 0; u < 32; ++u) {
                const int gc = 32 * k + u;
                wreg[32 * k + u] = (gc < 126) ? W1[(4 * n + k) * 126 + gc] : 0.f;
            }
            wreg[128 + k] = b1[4 * n + k];
            wreg[132 + k] = sigf(tau_n1[4 * n + k]);
        }
        gAl = sigf(tau_m1[n]);
    } else if (t >= 256 && t < 356) {              // C
        const int q = t - 256;
        #pragma unroll
        for (int k = 0; k < 4; ++k) {
            #pragma unroll
            for (int u = 0; u < 38; ++u) {
                const int gc = 38 * k + u;
                wreg[38 * k + u] = (gc < 150) ? W2[(4 * q + k) * 150 + gc] : 0.f;
            }
            wreg[152 + k] = b2[4 * q + k];
            wreg[156 + k] = sigf(tau_n2[4 * q + k]);
        }
        gAl = sigf(tau_m2[q]);
    } else if (t >= 356 && t < 364) {              // R (+md on 356/357)
        const int rr = t - 356;
        const int row = (rr < 4) ? 0 : 100;
        #pragma unroll
        for (int u = 0; u < 25; ++u) wreg[u] = Wd[row + 25 * (rr & 3) + u];
        if (rr < 2) { gAl = sigf(tau_md[rr]); gBias = bd[rr]; }
    } else if (t >= 384 && t < 484) {              // B
        const int q = t - 384;
        #pragma unroll
        for (int u = 0; u < 100; ++u) {
            wreg[u]       = Wxp[q * 200 + u];         // s2 cols
            wreg[100 + u] = Wxp[q * 200 + 100 + u];   // ls cols
        }
        gBias = bxp[q];
    }

    // dot of 100-elem LDS vector with wreg[wb..wb+99]
    auto dot100 = [&](int wb, const float* v) {
        float a0=0.f, a1=0.f, a2=0.f, a3=0.f;
        #pragma unroll
        for (int u4 = 0; u4 < 25; ++u4) {
            const float4 q4 = *reinterpret_cast<const float4*>(v + 4 * u4);
            a0 = fmaf(wreg[wb + 4*u4 + 0], q4.x, a0);
            a1 = fmaf(wreg[wb + 4*u4 + 1], q4.y, a1);
            a2 = fmaf(wreg[wb + 4*u4 + 2], q4.z, a2);
            a3 = fmaf(wreg[wb + 4*u4 + 3], q4.w, a3);
        }
        return (a0 + a1) + (a2 + a3);
    };

    // L1 neuron step over kin1 buffer k1 = [xt(k), s1(k-1)] (R1-proven math)
    auto l1_compute = [&](const float* k1) {
        float pr0 = wreg[128], pr1 = wreg[129], pr2 = wreg[130], pr3 = wreg[131];
        #pragma unroll
        for (int u4 = 0; u4 < 8; ++u4) {
            const float4 a0 = *reinterpret_cast<const float4*>(k1 +      4 * u4);
            const float4 a1 = *reinterpret_cast<const float4*>(k1 + 32 + 4 * u4);
            const float4 a2 = *reinterpret_cast<const float4*>(k1 + 64 + 4 * u4);
            const float4 a3 = *reinterpret_cast<const float4*>(k1 + 96 + 4 * u4);
            pr0 = fmaf(wreg[      4*u4+0], a0.x, pr0); pr0 = fmaf(wreg[      4*u4+1], a0.y, pr0);
            pr0 = fmaf(wreg[      4*u4+2], a0.z, pr0); pr0 = fmaf(wreg[      4*u4+3], a0.w, pr0);
            pr1 = fmaf(wreg[ 32 + 4*u4+0], a1.x, pr1); pr1 = fmaf(wreg[ 32 + 4*u4+1], a1.y, pr1);
            pr1 = fmaf(wreg[ 32 + 4*u4+2], a1.z, pr1); pr1 = fmaf(wreg[ 32 + 4*u4+3], a1.w, pr1);
            pr2 = fmaf(wreg[ 64 + 4*u4+0], a2.x, pr2); pr2 = fmaf(wreg[ 64 + 4*u4+1], a2.y, pr2);
            pr2 = fmaf(wreg[ 64 + 4*u4+2], a2.z, pr2); pr2 = fmaf(wreg[ 64 + 4*u4+3], a2.w, pr2);
            pr3 = fmaf(wreg[ 96 + 4*u4+0], a3.x, pr3); pr3 = fmaf(wreg[ 96 + 4*u4+1], a3.y, pr3);
            pr3 = fmaf(wreg[ 96 + 4*u4+2], a3.z, pr3); pr3 = fmaf(wreg[ 96 + 4*u4+3], a3.w, pr3);
        }
        const float d0 = wreg[132] * gA + (1.f - wreg[132]) * pr0;
        const float d1 = wreg[133] * gB + (1.f - wreg[133]) * pr1;
        const float d2 = wreg[134] * gC + (1.f - wreg[134]) * pr2;
        const float d3 = wreg[135] * gD + (1.f - wreg[135]) * pr3;
        gA = d0; gB = d1; gC = d2; gD = d3;
        const float sum = ((d0 + d1) + d2) + d3;
        gM = gAl * gM + (1.f - gAl) * sum - gS;
        gS = (gM - 1.0f > 0.f) ? 1.f : 0.f;
    };

    __syncthreads();
    // P1: xt(0) -> kin1[0]
    if (t >= 364 && t < 370) {
        const int i0 = t - 364;
        const float* xb = x + (size_t)blk * SEQ * IND;
        *reinterpret_cast<float4*>(&kin1[0][4 * i0])        = *reinterpret_cast<const float4*>(xb + 4 * i0);
        *reinterpret_cast<float4*>(&kin1[0][4 * (i0 + 6)])  = *reinterpret_cast<const float4*>(xb + 4 * (i0 + 6));
        *reinterpret_cast<float4*>(&kin1[0][4 * (i0 + 12)]) = *reinterpret_cast<const float4*>(xb + 4 * (i0 + 12));
        if (i0 == 0)
            *reinterpret_cast<float4*>(&kin1[0][72]) = *reinterpret_cast<const float4*>(xb + 72);
    }
    __syncthreads();
    // P2: s1(0) from kin1[0]; xt(1) -> kin1[1]
    if (t >= 200 && t < 250) {
        l1_compute(kin1[0]);
        const int n = t - 200;
        kin1[1][76 + n] = gS;
        const int w = (n >= 38) ? 1 : 0;
        kin2[0][w][n - 38 * w] = gS;
    } else if (t >= 364 && t < 370) {
        const int i0 = t - 364;
        const float* xb = x + ((size_t)blk * SEQ + 1) * IND;
        *reinterpret_cast<float4*>(&kin1[1][4 * i0])        = *reinterpret_cast<const float4*>(xb + 4 * i0);
        *reinterpret_cast<float4*>(&kin1[1][4 * (i0 + 6)])  = *reinterpret_cast<const float4*>(xb + 4 * (i0 + 6));
        *reinterpret_cast<float4*>(&kin1[1][4 * (i0 + 12)]) = *reinterpret_cast<const float4*>(xb + 4 * (i0 + 12));
        if (i0 == 0)
            *reinterpret_cast<float4*>(&kin1[1][72]) = *reinterpret_cast<const float4*>(xb + 72);
    }
    __syncthreads();

    for (int j = 0; j < SEQ; ++j) {
        const int pc = j & 1, pn = (j + 1) & 1;
        // ================= alpha =================
        if (t < 200) {
            pE = dot100(0, (t & 1) ? lbP : lmP);                 // stage2-early
        } else if (t >= 256 && t < 356) {
            // L2 neuron: 4 rows over kin2[pc] windows, in-thread m2/s2
            float pr0 = wreg[152], pr1 = wreg[153], pr2 = wreg[154], pr3 = wreg[155];
            #pragma unroll
            for (int u4 = 0; u4 < 9; ++u4) {
                const float4 v0 = *reinterpret_cast<const float4*>(&kin2[pc][0][4 * u4]);
                pr0 = fmaf(wreg[      4*u4+0], v0.x, pr0); pr0 = fmaf(wreg[      4*u4+1], v0.y, pr0);
                pr0 = fmaf(wreg[      4*u4+2], v0.z, pr0); pr0 = fmaf(wreg[      4*u4+3], v0.w, pr0);
                const float4 v1 = *reinterpret_cast<const float4*>(&kin2[pc][1][4 * u4]);
                pr1 = fmaf(wreg[ 38 + 4*u4+0], v1.x, pr1); pr1 = fmaf(wreg[ 38 + 4*u4+1], v1.y, pr1);
                pr1 = fmaf(wreg[ 38 + 4*u4+2], v1.z, pr1); pr1 = fmaf(wreg[ 38 + 4*u4+3], v1.w, pr1);
                const float4 v2 = *reinterpret_cast<const float4*>(&kin2[pc][2][4 * u4]);
                pr2 = fmaf(wreg[ 76 + 4*u4+0], v2.x, pr2); pr2 = fmaf(wreg[ 76 + 4*u4+1], v2.y, pr2);
                pr2 = fmaf(wreg[ 76 + 4*u4+2], v2.z, pr2); pr2 = fmaf(wreg[ 76 + 4*u4+3], v2.w, pr2);
                const float4 v3 = *reinterpret_cast<const float4*>(&kin2[pc][3][4 * u4]);
                pr3 = fmaf(wreg[114 + 4*u4+0], v3.x, pr3); pr3 = fmaf(wreg[114 + 4*u4+1], v3.y, pr3);
                pr3 = fmaf(wreg[114 + 4*u4+2], v3.z, pr3); pr3 = fmaf(wreg[114 + 4*u4+3], v3.w, pr3);
            }
            pr0 = fmaf(wreg[ 36], kin2[pc][0][36], pr0); pr0 = fmaf(wreg[ 37], kin2[pc][0][37], pr0);
            pr1 = fmaf(wreg[ 74], kin2[pc][1][36], pr1); pr1 = fmaf(wreg[ 75], kin2[pc][1][37], pr1);
            pr2 = fmaf(wreg[112], kin2[pc][2][36], pr2); pr2 = fmaf(wreg[113], kin2[pc][2][37], pr2);
            pr3 = fmaf(wreg[150], kin2[pc][3][36], pr3); pr3 = fmaf(wreg[151], kin2[pc][3][37], pr3);
            const float d0 = wreg[156] * gA + (1.f - wreg[156]) * pr0;
            const float d1 = wreg[157] * gB + (1.f - wreg[157]) * pr1;
            const float d2 = wreg[158] * gC + (1.f - wreg[158]) * pr2;
            const float d3 = wreg[159] * gD + (1.f - wreg[159]) * pr3;
            gA = d0; gB = d1; gC = d2; gD = d3;
            const float sum = ((d0 + d1) + d2) + d3;
            gM = gAl * gM + (1.f - gAl) * sum - gS;
            gS = (gM - 1.0f > 0.f) ? 1.f : 0.f;
            const int q = t - 256;
            s2P[q] = gS;
            const int col = 50 + q;
            const int w = (col >= 114) ? 3 : ((col >= 76) ? 2 : 1);
            kin2[pn][w][col - 38 * w] = gS;
        } else if (t >= 364 && t < 370) {
            if (j + 2 < SEQ) {
                const int i0 = t - 364;
                const float* xb = x + ((size_t)blk * SEQ + (j + 2)) * IND;
                xq0 = *reinterpret_cast<const float4*>(xb + 4 * i0);
                xq1 = *reinterpret_cast<const float4*>(xb + 4 * (i0 + 6));
                xq2 = *reinterpret_cast<const float4*>(xb + 4 * (i0 + 12));
                if (i0 == 0) xq3 = *reinterpret_cast<const float4*>(xb + 72);
            }
        } else if (t >= 384 && t < 484) {
            pE = dot100(100, lsP);                               // dx-early (WxL . ls)
        }
        __syncthreads();
        // ================= beta =================
        if (t >= 384 && t < 484) {
            const float dxS = dot100(0, s2P);                    // dx-late (WxS . s2)
            dxP[t - 384] = (dxS + pE) + gBias;
        } else if (t >= 200 && t < 250) {
            if (j < SEQ - 1) l1_compute(kin1[pn]);               // s1(j+1)
        } else if (t >= 364 && t < 370) {
            if (j + 2 < SEQ) {
                const int i0 = t - 364;
                *reinterpret_cast<float4*>(&kin1[pc][4 * i0])        = xq0;
                *reinterpret_cast<float4*>(&kin1[pc][4 * (i0 + 6)])  = xq1;
                *reinterpret_cast<float4*>(&kin1[pc][4 * (i0 + 12)]) = xq2;
                if (i0 == 0) *reinterpret_cast<float4*>(&kin1[pc][72]) = xq3;
            }
        } else if (t >= 356 && t < 364) {
            float sV = 0.f;
            const int base = 25 * ((t - 356) & 3);
            #pragma unroll
            for (int u = 0; u < 25; ++u) sV = fmaf(wreg[u], lsP[base + u], sV);
            const int o = t - 356;
            const int sb = 36 + 4 * o;                           // R lanes = wave-5 lanes 36..43
            const float v0 = __shfl(sV, sb + 0, 64);
            const float v1 = __shfl(sV, sb + 1, 64);
            const float v2 = __shfl(sV, sb + 2, 64);
            const float v3 = __shfl(sV, sb + 3, 64);
            if (o < 2 && j >= 1) {
                const float dot = ((v0 + v1) + (v2 + v3)) + gBias;
                gM = gAl * gM + (1.f - gAl) * dot;               // md(j-1)
                if (j >= 2) gS += gM;
            }
        }
        __syncthreads();
        // ================= gamma =================
        if (t < 200) {
            const float late = dot100(100, dxP);                 // stage2-late
            const float tv = sigf((late + pE) + gBias);
            const float tvp = __shfl(tv, (t & 63) | 1, 64);      // partner (Wa) value
            if ((t & 1) == 0) {
                const int r = t >> 1;
                const float lm = lmP[r], lb = lbP[r], ls = lsP[r], dxv = dxP[r];
                const float lbN = tvp * lb + (1.f - tvp) * ls;
                const float Bv  = 1.6f + 1.8f * lbN;
                const float lmN = lm * tv + (1.f - tv) * dxv - Bv * ls;
                const float lsN = (lmN - Bv > 0.f) ? 1.f : 0.f;
                lmP[r] = lmN; lbP[r] = lbN; lsP[r] = lsN;
            }
        } else if (t >= 200 && t < 250) {
            if (j < SEQ - 1) {                                   // s1(j+1) -> kin buffers
                const int n = t - 200;
                kin1[pc][76 + n] = gS;
                const int w = (n >= 38) ? 1 : 0;
                kin2[pn][w][n - 38 * w] = gS;
            }
        }
        __syncthreads();
    }

    // ================= epilogue: md(SEQ-1) from ls(SEQ-1) =================
    if (t >= 356 && t < 364) {
        float sV = 0.f;
        const int base = 25 * ((t - 356) & 3);
        #pragma unroll
        for (int u = 0; u < 25; ++u) sV = fmaf(wreg[u], lsP[base + u], sV);
        const int o = t - 356;
        const int sb = 36 + 4 * o;
        const float v0 = __shfl(sV, sb + 0, 64);
        const float v1 = __shfl(sV, sb + 1, 64);
        const float v2 = __shfl(sV, sb + 2, 64);
        const float v3 = __shfl(sV, sb + 3, 64);
        if (o < 2) {
            const float dot = ((v0 + v1) + (v2 + v3)) + gBias;
            gM = gAl * gM + (1.f - gAl) * dot;
            gS += gM;
            out[blk * 2 + o] = gS;
        }
    }
}

extern "C" void kernel_launch(void* const* d_in, const int* in_sizes, int n_in,
                              void* d_out, int out_size, void* d_ws, size_t ws_size,
                              hipStream_t stream) {
    const float* x      = (const float*)d_in[0];
    const float* W1     = (const float*)d_in[1];
    const float* b1     = (const float*)d_in[2];
    const float* tau_m1 = (const float*)d_in[3];
    const float* tau_n1 = (const float*)d_in[4];
    const float* W2     = (const float*)d_in[5];
    const float* b2     = (const float*)d_in[6];
    const float* tau_m2 = (const float*)d_in[7];
    const float* tau_n2 = (const float*)d_in[8];
    const float* Wx     = (const float*)d_in[9];
    const float* bx     = (const float*)d_in[10];
    const float* Wm     = (const float*)d_in[11];
    const float* bm     = (const float*)d_in[12];
    const float* Wa     = (const float*)d_in[13];
    const float* ba     = (const float*)d_in[14];
    const float* Wd     = (const float*)d_in[15];
    const float* bd     = (const float*)d_in[16];
    const float* tau_md = (const float*)d_in[17];
    float* out = (float*)d_out;

    const int batch = in_sizes[0] / (SEQ * IND);   // 256
    dhsnn_fwd<<<batch, 512, 0, stream>>>(x, W1, b1, tau_m1, tau_n1,
                                         W2, b2, tau_m2, tau_n2,
                                         Wx, bx, Wm, bm, Wa, ba,
                                         Wd, bd, tau_md, out);
}

// Round 9
// 6999.077 us; speedup vs baseline: 3.7462x; 3.7462x over previous
//
#include <hip/hip_runtime.h>
#include <math.h>

#define SEQ 1000
#define IND 76
#define PIDX(i) ((((i)/25)*28) + ((i)%25))   // 25-chunk -> 28-stride padded layout

__device__ __forceinline__ float sigf(float v) { return 1.0f / (1.0f + expf(-v)); }

// w2pk[r][40]: masked branch window of W2 row r (38 cols, zero-padded to 40).
__global__ void pack_w2(const float* __restrict__ W2, float* __restrict__ w2pk) {
    const int i = blockIdx.x * 256 + threadIdx.x;
    if (i >= 400 * 40) return;
    const int r = i / 40, u = i - 40 * r;
    const int col = 38 * (r & 3) + u;
    w2pk[i] = (u < 38 && col < 150) ? W2[r * 150 + col] : 0.f;
}

// 1024 threads, 3 barriers/step, 4 waves/SIMD.
//  SS t<800:   liquid neuron n8=t>>3, lane o8=t&7 (o8<4: Wm row n8 quarter qt=o8;
//              o8>=4: Wa row n8 quarter qt=o8-4). wreg[0..24]=mem cols (stage2-early),
//              wreg[25..49]=dx cols (stage2-late). ALSO L2 packed row r2row=t>>1 half hh=t&1
//              (20 cols STREAMED from w2pk); d2 state at hh==0; m2/s2 + liquid at o8==0.
//  DXL t[800,1000): i1=t-800. dx row qx=i1>>1 half hx=i1&1 (50+50 cols STREAMED from Wx);
//              L1 row i1 (32 masked cols in wreg[0..31]); m1/s1 at (i1&3)==0.
//  X t[1000,1019): xt prefetch (issue alpha, write beta); t[1000,1008): r2 reduce (beta);
//              t 1000/1001: readout md owner (gamma).
__global__ __launch_bounds__(1024) void dhsnn_fwd(
    const float* __restrict__ x,
    const float* __restrict__ W1, const float* __restrict__ b1,
    const float* __restrict__ tau_m1, const float* __restrict__ tau_n1,
    const float* __restrict__ b2, const float* __restrict__ tau_m2,
    const float* __restrict__ tau_n2,
    const float* __restrict__ Wxp, const float* __restrict__ bxp,
    const float* __restrict__ Wm, const float* __restrict__ bm,
    const float* __restrict__ Wa, const float* __restrict__ ba,
    const float* __restrict__ Wd, const float* __restrict__ bd,
    const float* __restrict__ tau_md,
    const float* __restrict__ w2pk,
    float* __restrict__ out)
{
    const int t   = (int)threadIdx.x;
    const int blk = (int)blockIdx.x;

    __shared__ __align__(16) float kin1[2][128];   // [0..75] xt, [76..125] s1, [126..127]=0
    __shared__ __align__(16) float kin2[2][4][40]; // windows of [s1(50); s2(100)], [38..39]=0
    __shared__ __align__(16) float s2P[100];       // linear (read at 50-offsets)
    __shared__ __align__(16) float lsP[100];       // linear
    __shared__ __align__(16) float dxP[112];       // PIDX (read at 28-stride quarters)
    __shared__ __align__(16) float lmP[112];
    __shared__ __align__(16) float lbP[112];
    __shared__ __align__(16) float rpart[200];
    __shared__ __align__(16) float r2v[8];

    for (int i = t; i < 256; i += 1024) (&kin1[0][0])[i] = 0.f;
    for (int i = t; i < 320; i += 1024) (&kin2[0][0][0])[i] = 0.f;
    for (int i = t; i < 100; i += 1024) { s2P[i] = 0.f; lsP[i] = 0.f; }
    for (int i = t; i < 112; i += 1024) { dxP[i] = 0.f; lmP[i] = 0.f; lbP[i] = 0.f; }
    for (int i = t; i < 200; i += 1024) rpart[i] = 0.f;
    if (t < 8) r2v[t] = 0.f;

    const int lane = t & 63;
    const int l8   = lane & ~7;
    const int l4   = lane & ~3;
    // SS indices
    const int n8 = t >> 3, o8 = t & 7, qt = o8 & 3;
    const int r2row = t >> 1, hh = t & 1, c2 = r2row & 3;
    // DXL indices
    const int i1 = t - 800, qx = i1 >> 1, hx = i1 & 1, k1 = i1 & 3;

    float wreg[50];
    #pragma unroll
    for (int i = 0; i < 50; ++i) wreg[i] = 0.f;
    // role-unioned scalars:
    //  SS:  sA=b2(row), sB=bt2(row), sC=d2, sD=pE(early dot), sE=al2, sF=m2, sG=s2spk,
    //       sH=bm, sI=ba, sJ=wd
    //  DXL: sA=b1, sB=bt1, sC=d1, sD=pEdx, sE=al1, sF=m1, sG=s1spk, sH=bx
    //  md:  sE=alpha_d, sF=mdr, sG=accr, sH=bd
    float sA=0.f,sB=0.f,sC=0.f,sD=0.f,sE=0.f,sF=0.f,sG=0.f,sH=0.f,sI=0.f,sJ=0.f;
    float4 xq = make_float4(0.f,0.f,0.f,0.f);

    // ---- init ----
    if (t < 800) {
        const float* Wrow = (o8 >= 4 ? Wa : Wm) + n8 * 200;
        #pragma unroll
        for (int u = 0; u < 25; ++u) {
            wreg[u]      = Wrow[100 + 25 * qt + u];   // mem cols (early)
            wreg[25 + u] = Wrow[25 * qt + u];         // dx cols (late)
        }
        sA = b2[r2row];
        sB = sigf(tau_n2[r2row]);
        if (o8 == 0) { sE = sigf(tau_m2[n8]); sH = bm[n8]; sI = ba[n8]; }
        if (t < 200) sJ = Wd[t];
    } else if (t < 1000) {
        #pragma unroll
        for (int u = 0; u < 32; ++u) {
            const int gc = 32 * k1 + u;
            wreg[u] = (gc < 126) ? W1[i1 * 126 + gc] : 0.f;
        }
        sA = b1[i1];
        sB = sigf(tau_n1[i1]);
        if (k1 == 0) sE = sigf(tau_m1[i1 >> 2]);
        if (hx == 0) sH = bxp[qx];
    } else if (t == 1000 || t == 1001) {
        sE = sigf(tau_md[t - 1000]);
        sH = bd[t - 1000];
    }

    // L1 row over kin1[p] cols [32*k1, +32); d1 update; 4-lane gather -> m1/s1 at k1==0
    auto l1_compute = [&](int p) {
        const float* ap = kin1[p] + 32 * k1;
        float p0 = sA, p1 = 0.f, p2 = 0.f, p3 = 0.f;
        #pragma unroll
        for (int u4 = 0; u4 < 8; ++u4) {
            const float4 av = *reinterpret_cast<const float4*>(ap + 4 * u4);
            p0 = fmaf(wreg[4*u4+0], av.x, p0);
            p1 = fmaf(wreg[4*u4+1], av.y, p1);
            p2 = fmaf(wreg[4*u4+2], av.z, p2);
            p3 = fmaf(wreg[4*u4+3], av.w, p3);
        }
        const float proj = (p0 + p1) + (p2 + p3);
        sC = sB * sC + (1.f - sB) * proj;               // d1
        const float d0 = __shfl(sC, l4 + 0, 64);
        const float d1 = __shfl(sC, l4 + 1, 64);
        const float d2 = __shfl(sC, l4 + 2, 64);
        const float d3 = __shfl(sC, l4 + 3, 64);
        if (k1 == 0) {
            const float sum = ((d0 + d1) + d2) + d3;
            sF = sE * sF + (1.f - sE) * sum - sG;       // m1
            sG = (sF - 1.0f > 0.f) ? 1.f : 0.f;         // s1 spike
        }
    };
    // 50-col streamed dot
    auto dot50 = [&](const float* w, const float* a) {
        float f0=0.f, f1=0.f, f2=0.f, f3=0.f;
        #pragma unroll
        for (int u4 = 0; u4 < 12; ++u4) {
            const float4 wv = *reinterpret_cast<const float4*>(w + 4 * u4);
            const float4 av = *reinterpret_cast<const float4*>(a + 4 * u4);
            f0 = fmaf(wv.x, av.x, f0); f1 = fmaf(wv.y, av.y, f1);
            f2 = fmaf(wv.z, av.z, f2); f3 = fmaf(wv.w, av.w, f3);
        }
        f0 = fmaf(w[48], a[48], f0);
        f1 = fmaf(w[49], a[49], f1);
        return (f0 + f1) + (f2 + f3);
    };

    __syncthreads();
    // P1: lb init; xt(0) -> kin1[0]
    if (t < 100) lbP[PIDX(t)] = 1.6f;
    if (t >= 1000 && t < 1019) {
        const int i0 = t - 1000;
        *reinterpret_cast<float4*>(&kin1[0][4 * i0]) =
            *reinterpret_cast<const float4*>(x + (size_t)blk * SEQ * IND + 4 * i0);
    }
    __syncthreads();
    // P2: L1(0) -> s1(0) into kin1[1].s1 + kin2[0] window; xt(1) -> kin1[1]
    if (t >= 800 && t < 1000) {
        l1_compute(0);
        if (k1 == 0) {
            const int n1 = i1 >> 2;
            kin1[1][76 + n1] = sG;
            const int w = (n1 >= 38) ? 1 : 0;
            kin2[0][w][n1 - 38 * w] = sG;
        }
    } else if (t >= 1000 && t < 1019) {
        const int i0 = t - 1000;
        *reinterpret_cast<float4*>(&kin1[1][4 * i0]) =
            *reinterpret_cast<const float4*>(x + ((size_t)blk * SEQ + 1) * IND + 4 * i0);
    }
    __syncthreads();

    for (int j = 0; j < SEQ; ++j) {
        const int pc = j & 1, pn = pc ^ 1;
        // ===== alpha: L2(j)+m2/s2; stage2-early; dx-early; L1(j+1); rpart; x issue =====
        if (t < 800) {
            {   // L2(j): half row streamed from w2pk, over kin2[pc] window
                const float* wv = w2pk + r2row * 40 + 20 * hh;
                const float* kw = &kin2[pc][c2][20 * hh];
                float a0=0.f, a1=0.f, a2=0.f, a3=0.f;
                #pragma unroll
                for (int u4 = 0; u4 < 5; ++u4) {
                    const float4 w4 = *reinterpret_cast<const float4*>(wv + 4 * u4);
                    const float4 av = *reinterpret_cast<const float4*>(kw + 4 * u4);
                    a0 = fmaf(w4.x, av.x, a0); a1 = fmaf(w4.y, av.y, a1);
                    a2 = fmaf(w4.z, av.z, a2); a3 = fmaf(w4.w, av.w, a3);
                }
                const float hsum = (a0 + a1) + (a2 + a3);
                const float hoth = __shfl_xor(hsum, 1, 64);
                if (hh == 0) {
                    const float proj = sA + (hsum + hoth);
                    sC = sB * sC + (1.f - sB) * proj;            // d2
                }
                const float d0 = __shfl(sC, l8 + 0, 64);
                const float d1 = __shfl(sC, l8 + 2, 64);
                const float d2 = __shfl(sC, l8 + 4, 64);
                const float d3 = __shfl(sC, l8 + 6, 64);
                if (o8 == 0) {
                    const float sum = ((d0 + d1) + d2) + d3;
                    sF = sE * sF + (1.f - sE) * sum - sG;        // m2
                    sG = (sF - 1.0f > 0.f) ? 1.f : 0.f;          // s2 spike
                    s2P[n8] = sG;
                    const int col = 50 + n8;
                    const int w = (col >= 114) ? 3 : ((col >= 76) ? 2 : 1);
                    kin2[pn][w][col - 38 * w] = sG;
                }
            }
            {   // stage2-early quarter over lm (o8<4) / lb (o8>=4)
                const float* ap = (o8 >= 4 ? lbP : lmP) + 28 * qt;
                float e0=0.f, e1=0.f, e2=0.f, e3=0.f;
                #pragma unroll
                for (int u4 = 0; u4 < 6; ++u4) {
                    const float4 av = *reinterpret_cast<const float4*>(ap + 4 * u4);
                    e0 = fmaf(wreg[4*u4+0], av.x, e0);
                    e1 = fmaf(wreg[4*u4+1], av.y, e1);
                    e2 = fmaf(wreg[4*u4+2], av.z, e2);
                    e3 = fmaf(wreg[4*u4+3], av.w, e3);
                }
                e0 = fmaf(wreg[24], ap[24], e0);
                sD = (e0 + e1) + (e2 + e3);                      // pE
            }
            if (t < 200) rpart[t] = sJ * lsP[t % 100];
        } else if (t < 1000) {
            if (j < SEQ - 1) l1_compute(pn);                     // s1(j+1)
            sD = dot50(Wxp + qx * 200 + 100 + 50 * hx, lsP + 50 * hx);  // dx-early
        } else if (t < 1019) {
            if (j + 2 < SEQ)
                xq = *reinterpret_cast<const float4*>(
                    x + ((size_t)blk * SEQ + (j + 2)) * IND + 4 * (t - 1000));
        }
        __syncthreads();
        // ===== beta: dx-late -> dxP; r2 reduce; xt write =====
        if (t >= 800 && t < 1000) {
            const float lt = dot50(Wxp + qx * 200 + 50 * hx, s2P + 50 * hx);
            const float lsum = lt + __shfl_xor(lt, 1, 64);
            const float esum = sD + __shfl_xor(sD, 1, 64);
            if (hx == 0) dxP[PIDX(qx)] = (lsum + esum) + sH;
        } else if (t >= 1000) {
            if (t < 1008) {
                float sv = 0.f;
                #pragma unroll
                for (int u = 0; u < 25; ++u) sv += rpart[25 * (t - 1000) + u];
                r2v[t - 1000] = sv;
            }
            if (t < 1019 && j + 2 < SEQ)
                *reinterpret_cast<float4*>(&kin1[pc][4 * (t - 1000)]) = xq;
        }
        __syncthreads();
        // ===== gamma: stage2-late + sigmoids + liquid; s1 write; md =====
        if (t < 800) {
            const float* ap = dxP + 28 * qt;
            float e0=0.f, e1=0.f, e2=0.f, e3=0.f;
            #pragma unroll
            for (int u4 = 0; u4 < 6; ++u4) {
                const float4 av = *reinterpret_cast<const float4*>(ap + 4 * u4);
                e0 = fmaf(wreg[25 + 4*u4 + 0], av.x, e0);
                e1 = fmaf(wreg[25 + 4*u4 + 1], av.y, e1);
                e2 = fmaf(wreg[25 + 4*u4 + 2], av.z, e2);
                e3 = fmaf(wreg[25 + 4*u4 + 3], av.w, e3);
            }
            e0 = fmaf(wreg[49], ap[24], e0);
            const float Tq = ((e0 + e1) + (e2 + e3)) + sD;       // late quarter + early quarter
            const float T0 = __shfl(Tq, l8 + 0, 64);
            const float T1 = __shfl(Tq, l8 + 1, 64);
            const float T2 = __shfl(Tq, l8 + 2, 64);
            const float T3 = __shfl(Tq, l8 + 3, 64);
            const float T4 = __shfl(Tq, l8 + 4, 64);
            const float T5 = __shfl(Tq, l8 + 5, 64);
            const float T6 = __shfl(Tq, l8 + 6, 64);
            const float T7 = __shfl(Tq, l8 + 7, 64);
            if (o8 == 0) {
                const float tm = sigf(((T0 + T1) + (T2 + T3)) + sH);
                const float ta = sigf(((T4 + T5) + (T6 + T7)) + sI);
                const float lm = lmP[PIDX(n8)], lb = lbP[PIDX(n8)];
                const float ls = lsP[n8],       dxv = dxP[PIDX(n8)];
                const float lbN = ta * lb + (1.f - ta) * ls;
                const float Bv  = 1.6f + 1.8f * lbN;
                const float lmN = lm * tm + (1.f - tm) * dxv - Bv * ls;
                const float lsN = (lmN - Bv > 0.f) ? 1.f : 0.f;
                lmP[PIDX(n8)] = lmN; lbP[PIDX(n8)] = lbN; lsP[n8] = lsN;
            }
        } else if (t < 1000) {
            if (k1 == 0 && j < SEQ - 1) {                        // s1(j+1) -> kin buffers
                const int n1 = i1 >> 2;
                kin1[pc][76 + n1] = sG;
                const int w = (n1 >= 38) ? 1 : 0;
                kin2[pn][w][n1 - 38 * w] = sG;
            }
        } else if ((t == 1000 || t == 1001) && j >= 1) {
            const int o = t - 1000;
            const float dot = ((r2v[4*o] + r2v[4*o+1]) + (r2v[4*o+2] + r2v[4*o+3])) + sH;
            sF = sE * sF + (1.f - sE) * dot;                     // md(j-1)
            if (j >= 2) sG += sF;                                // accr
        }
        __syncthreads();
    }

    // ===== epilogue: md(SEQ-1) over ls(SEQ-1) =====
    if (t < 200) rpart[t] = sJ * lsP[t % 100];
    __syncthreads();
    if (t >= 1000 && t < 1008) {
        float sv = 0.f;
        #pragma unroll
        for (int u = 0; u < 25; ++u) sv += rpart[25 * (t - 1000) + u];
        r2v[t - 1000] = sv;
    }
    __syncthreads();
    if (t == 1000 || t == 1001) {
        const int o = t - 1000;
        const float dot = ((r2v[4*o] + r2v[4*o+1]) + (r2v[4*o+2] + r2v[4*o+3])) + sH;
        sF = sE * sF + (1.f - sE) * dot;
        sG += sF;
        out[blk * 2 + o] = sG;
    }
}

extern "C" void kernel_launch(void* const* d_in, const int* in_sizes, int n_in,
                              void* d_out, int out_size, void* d_ws, size_t ws_size,
                              hipStream_t stream) {
    const float* x      = (const float*)d_in[0];
    const float* W1     = (const float*)d_in[1];
    const float* b1     = (const float*)d_in[2];
    const float* tau_m1 = (const float*)d_in[3];
    const float* tau_n1 = (const float*)d_in[4];
    const float* W2     = (const float*)d_in[5];
    const float* b2     = (const float*)d_in[6];
    const float* tau_m2 = (const float*)d_in[7];
    const float* tau_n2 = (const float*)d_in[8];
    const float* Wx     = (const float*)d_in[9];
    const float* bx     = (const float*)d_in[10];
    const float* Wm     = (const float*)d_in[11];
    const float* bm     = (const float*)d_in[12];
    const float* Wa     = (const float*)d_in[13];
    const float* ba     = (const float*)d_in[14];
    const float* Wd     = (const float*)d_in[15];
    const float* bd     = (const float*)d_in[16];
    const float* tau_md = (const float*)d_in[17];
    float* out  = (float*)d_out;
    float* w2pk = (float*)d_ws;                       // 400*40 = 16000 floats

    pack_w2<<<(400 * 40 + 255) / 256, 256, 0, stream>>>(W2, w2pk);

    const int batch = in_sizes[0] / (SEQ * IND);      // 256
    dhsnn_fwd<<<batch, 1024, 0, stream>>>(x, W1, b1, tau_m1, tau_n1,
                                          b2, tau_m2, tau_n2,
                                          Wx, bx, Wm, bm, Wa, ba,
                                          Wd, bd, tau_md,
                                          w2pk, out);
}